// Round 6
// baseline (170.376 us; speedup 1.0000x reference)
//
#include <hip/hip_runtime.h>
#include <hip/hip_bf16.h>
#include <hip/hip_cooperative_groups.h>

namespace cg = cooperative_groups;

// out[b,h,i,j] = mask[b,h,i,j] - bias[h, i-j]
// bias depends only on d = i-j+1023 -> 8 x 2047 table (64 KiB), stored
// REVERSED: rtab[h][1023-i+j] so a row's j-sweep is ascending contiguous.
//
// Single cooperative kernel: phase 1 builds the table (2 diags/block),
// grid.sync(), phase 2 streams mask - bias (16 rows/block).

#define L_SEQ 1024
#define NDIAG (2 * L_SEQ - 1)   // 2047
#define NH 8
#define DIM 64

typedef float f32x4 __attribute__((ext_vector_type(4)));
// 4-byte-aligned variant for the shifted bias-window vector load
typedef float f32x4u __attribute__((ext_vector_type(4), aligned(4)));

__device__ __forceinline__ float silu_f(float x) {
    return x / (1.0f + __expf(-x));
}

__device__ __forceinline__ void mlp_diag(
    int d, int g, int tt, float* shrow,
    const float* __restrict__ W0, const float* __restrict__ b0,
    const float* __restrict__ W1, const float* __restrict__ b1,
    const float* __restrict__ W2, const float* __restrict__ b2,
    const float* __restrict__ Wf, const float* __restrict__ bf,
    float* __restrict__ rtab, bool act) {
    const float rel = (float)(d - (L_SEQ - 1));
    if (act) shrow[tt] = silu_f(rel * W0[tt] + b0[tt]);
    __syncthreads();
    float acc = 0.f;
    if (act) {
        acc = b1[tt];
        #pragma unroll
        for (int k = 0; k < DIM; ++k) acc += shrow[k] * W1[k * DIM + tt];
        acc = silu_f(acc);
    }
    __syncthreads();
    if (act) shrow[tt] = acc;
    __syncthreads();
    if (act) {
        acc = b2[tt];
        #pragma unroll
        for (int k = 0; k < DIM; ++k) acc += shrow[k] * W2[k * DIM + tt];
        acc = silu_f(acc);
    }
    __syncthreads();
    if (act) shrow[tt] = acc;
    __syncthreads();
    if (act && tt < NH) {
        float a = bf[tt];
        #pragma unroll
        for (int k = 0; k < DIM; ++k) a += shrow[k] * Wf[k * NH + tt];
        rtab[tt * NDIAG + (NDIAG - 1 - d)] = a;
    }
}

__global__ __launch_bounds__(256, 4) void fused_bias(
    const f32x4* __restrict__ mask,
    const float* __restrict__ W0, const float* __restrict__ b0,
    const float* __restrict__ W1, const float* __restrict__ b1,
    const float* __restrict__ W2, const float* __restrict__ b2,
    const float* __restrict__ Wf, const float* __restrict__ bf,
    float* __restrict__ rtab, f32x4* __restrict__ out) {
    const int blk = blockIdx.x;          // 0..1023
    const int t = threadIdx.x;

    // ---- phase 1: build 2 diagonals (lanes 0..127 active) ----
    {
        __shared__ float sh[2][DIM];
        const int g = t >> 6;            // 0..3
        const int tt = t & 63;
        const int d = blk * 2 + g;       // valid when g < 2
        const bool act = (g < 2) && (d < NDIAG);
        mlp_diag(d, g, tt, sh[g & 1], W0, b0, W1, b1, W2, b2, Wf, bf, rtab, act);
    }
    __threadfence();                     // device-scope release of rtab
    cg::this_grid().sync();              // acquire: cross-XCD visibility

    // ---- phase 2: streaming apply, 16 rows (8 i x 2 b) per block ----
    const int h = blk >> 7;              // 0..7
    const int i0 = (blk & 127) << 3;     // 0..1016
    const int j0 = t << 2;

    #pragma unroll
    for (int r = 0; r < 8; ++r) {
        const int i = i0 + r;
        const float* rt = rtab + h * NDIAG + (L_SEQ - 1 - i);
        const f32x4u v = *(const f32x4u*)(rt + j0);   // bias[h,i,4t..4t+3]
        #pragma unroll
        for (int b = 0; b < 2; ++b) {
            const int idx = ((b * NH + h) * L_SEQ + i) * 256 + t;
            const f32x4 m = mask[idx];
            f32x4 o;
            o.x = m.x - v.x;
            o.y = m.y - v.y;
            o.z = m.z - v.z;
            o.w = m.w - v.w;
            out[idx] = o;
        }
    }
}

// ---------- fallback path (R4, proven): two plain launches ----------

__global__ __launch_bounds__(256) void build_bias_table(
    const float* __restrict__ W0, const float* __restrict__ b0,
    const float* __restrict__ W1, const float* __restrict__ b1,
    const float* __restrict__ W2, const float* __restrict__ b2,
    const float* __restrict__ Wf, const float* __restrict__ bf,
    float* __restrict__ rtab) {
    const int g = threadIdx.x >> 6;
    const int tt = threadIdx.x & 63;
    const int d = blockIdx.x * 4 + g;
    __shared__ float sh[4][DIM];
    mlp_diag(d, g, tt, sh[g], W0, b0, W1, b1, W2, b2, Wf, bf, rtab,
             d < NDIAG);
}

__global__ __launch_bounds__(256) void apply_bias(
    const f32x4* __restrict__ mask, const float* __restrict__ rtab,
    f32x4* __restrict__ out) {
    const int row = blockIdx.x;
    const int i = row & (L_SEQ - 1);
    const int h = (row >> 10) & (NH - 1);
    const float* rt = rtab + h * NDIAG + (L_SEQ - 1 - i);
    const int t = threadIdx.x;
    const int idx = row * 256 + t;
    const f32x4u v = *(const f32x4u*)(rt + (t << 2));
    const f32x4 m = mask[idx];
    f32x4 o;
    o.x = m.x - v.x;
    o.y = m.y - v.y;
    o.z = m.z - v.z;
    o.w = m.w - v.w;
    out[idx] = o;
}

extern "C" void kernel_launch(void* const* d_in, const int* in_sizes, int n_in,
                              void* d_out, int out_size, void* d_ws, size_t ws_size,
                              hipStream_t stream) {
    const f32x4* mask = (const f32x4*)d_in[0];
    const float* W0 = (const float*)d_in[4];
    const float* b0 = (const float*)d_in[5];
    const float* W1 = (const float*)d_in[6];
    const float* b1 = (const float*)d_in[7];
    const float* W2 = (const float*)d_in[8];
    const float* b2 = (const float*)d_in[9];
    const float* Wf = (const float*)d_in[10];
    const float* bf = (const float*)d_in[11];
    f32x4* out = (f32x4*)d_out;
    float* rtab = (float*)d_ws;   // NH * NDIAG floats = 64 KiB

    void* args[] = {(void*)&mask, (void*)&W0, (void*)&b0, (void*)&W1,
                    (void*)&b1,   (void*)&W2, (void*)&b2, (void*)&Wf,
                    (void*)&bf,   (void*)&rtab, (void*)&out};
    hipError_t err = hipLaunchCooperativeKernel(
        (void*)fused_bias, dim3(1024), dim3(256), args, 0, stream);

    if (err != hipSuccess) {
        // fallback: proven two-kernel path
        build_bias_table<<<(NDIAG + 3) / 4, 256, 0, stream>>>(
            W0, b0, W1, b1, W2, b2, Wf, bf, rtab);
        apply_bias<<<out_size / L_SEQ, 256, 0, stream>>>(mask, rtab, out);
    }
}

// Round 8
// 48.436 us; speedup vs baseline: 3.5176x; 3.5176x over previous
//
#include <hip/hip_runtime.h>
#include <hip/hip_bf16.h>

// out[b,h,i,j] = mask[b,h,i,j] - bias[h, i-j]
// bias depends only on d = i-j+1023 -> 8 x 2047 table (64 KiB), stored
// REVERSED: rtab[h][1023-i+j] so a row's j-sweep is ascending contiguous.
//
// SINGLE kernel, 256 blocks x 1024 threads, hand-rolled flag sync:
//   Phase 1: block b builds diagonals 8b..8b+7 (covers all 2047), one
//            release-scope atomicAdd per block to a single counter.
//   Sync:    t==0 acquire-polls counter==256 with s_sleep backoff.
//            Bounded spin + self-build fallback => no deadlock possible.
//   Phase 2: stream 64 rows (one (b,h) i-tile); tc=t&255 is j-column,
//            g4=t>>8 interleaves rows across the 4 wave-groups.
// Co-residency: 16 waves/block <= 32/CU, 4KB LDS, any VGPR count fits =>
// all 256 blocks resident on 256 CUs => spin completes.

#define L_SEQ 1024
#define NDIAG (2 * L_SEQ - 1)   // 2047
#define NH 8
#define DIM 64

typedef float f32x4 __attribute__((ext_vector_type(4)));
typedef float f32x4u __attribute__((ext_vector_type(4), aligned(4)));

__device__ __forceinline__ float silu_f(float x) {
    return x / (1.0f + __expf(-x));
}

// One diagonal per 64-lane group; ALL threads must call (uniform syncs).
__device__ __forceinline__ void mlp_one(
    int d, int tt, float* sh, bool act,
    const float* __restrict__ W0, const float* __restrict__ b0,
    const float* __restrict__ W1, const float* __restrict__ b1,
    const float* __restrict__ W2, const float* __restrict__ b2,
    const float* __restrict__ Wf, const float* __restrict__ bf,
    float* __restrict__ rtab) {
    const float rel = (float)(d - (L_SEQ - 1));
    if (act) sh[tt] = silu_f(rel * W0[tt] + b0[tt]);
    __syncthreads();
    float a = 0.f;
    if (act) {
        a = b1[tt];
        #pragma unroll
        for (int k = 0; k < DIM; ++k) a += sh[k] * W1[k * DIM + tt];
        a = silu_f(a);
    }
    __syncthreads();
    if (act) sh[tt] = a;
    __syncthreads();
    if (act) {
        a = b2[tt];
        #pragma unroll
        for (int k = 0; k < DIM; ++k) a += sh[k] * W2[k * DIM + tt];
        a = silu_f(a);
    }
    __syncthreads();
    if (act) sh[tt] = a;
    __syncthreads();
    if (act && tt < NH) {
        float o = bf[tt];
        #pragma unroll
        for (int k = 0; k < DIM; ++k) o += sh[k] * Wf[k * NH + tt];
        rtab[tt * NDIAG + (NDIAG - 1 - d)] = o;   // reversed store
    }
    __syncthreads();   // LDS row reusable after this
}

__global__ __launch_bounds__(1024) void fused(
    const f32x4* __restrict__ mask,
    const float* __restrict__ W0, const float* __restrict__ b0,
    const float* __restrict__ W1, const float* __restrict__ b1,
    const float* __restrict__ W2, const float* __restrict__ b2,
    const float* __restrict__ Wf, const float* __restrict__ bf,
    float* __restrict__ rtab, unsigned int* __restrict__ cnt,
    f32x4* __restrict__ out) {
    const int blk = blockIdx.x;          // 0..255
    const int t = threadIdx.x;           // 0..1023
    const int g = t >> 6;                // 64-lane group 0..15
    const int tt = t & 63;

    __shared__ float sh[16][DIM];
    __shared__ int ready;

    // ---- phase 1: build 8 diagonals (groups 0..7 active) ----
    {
        const int d = blk * 8 + g;
        const bool act = (g < 8) && (d < NDIAG);
        mlp_one(d, tt, sh[g], act, W0, b0, W1, b1, W2, b2, Wf, bf, rtab);
    }
    if (t == 0) {
        __hip_atomic_fetch_add(cnt, 1u, __ATOMIC_RELEASE,
                               __HIP_MEMORY_SCOPE_AGENT);
        int ok = 0;
        for (int it = 0; it < 32768; ++it) {   // bounded (~20 ms worst)
            if (__hip_atomic_load(cnt, __ATOMIC_ACQUIRE,
                                  __HIP_MEMORY_SCOPE_AGENT) >= 256u) {
                ok = 1; break;
            }
            __builtin_amdgcn_s_sleep(16);
        }
        ready = ok;
    }
    __syncthreads();

    // block -> (b_, h, i-tile): 2 * 8 * 16 = 256
    const int b_ = blk >> 7;             // 0..1
    const int h = (blk >> 4) & 7;        // 0..7
    const int i0 = (blk & 15) << 6;      // 0,64,...,960

    // ---- fallback (only if residency assumption ever breaks) ----
    if (!ready) {
        // rows i0..i0+63 need diags d in [i0, i0+1086]
        for (int p = 0; p < 68; ++p) {
            const int d = i0 + p * 16 + g;
            const bool act = (d <= i0 + 1086) && (d < NDIAG);
            mlp_one(d, tt, sh[g], act, W0, b0, W1, b1, W2, b2, Wf, bf, rtab);
        }
    }

    // ---- phase 2: stream 64 rows; 4 wave-groups interleave rows ----
    const int tc = t & 255;              // j-column (vec4 index)
    const int g4 = t >> 8;               // 0..3: row interleave
    const int j0 = tc << 2;
    const float* rth = rtab + h * NDIAG + (L_SEQ - 1);
    const long rowbase = (long)((b_ * NH + h) * L_SEQ + i0) * 256;
    const f32x4* mrow = mask + rowbase;
    f32x4* orow = out + rowbase;

    #pragma unroll 4
    for (int k = 0; k < 16; ++k) {
        const int r = g4 + (k << 2);     // rows g4, g4+4, ..., g4+60
        const int i = i0 + r;
        const f32x4u v = *(const f32x4u*)(rth - i + j0);  // bias[h,i,j0..+3]
        const f32x4 m = mrow[r * 256 + tc];
        f32x4 o;
        o.x = m.x - v.x;
        o.y = m.y - v.y;
        o.z = m.z - v.z;
        o.w = m.w - v.w;
        orow[r * 256 + tc] = o;
    }
}

extern "C" void kernel_launch(void* const* d_in, const int* in_sizes, int n_in,
                              void* d_out, int out_size, void* d_ws, size_t ws_size,
                              hipStream_t stream) {
    const f32x4* mask = (const f32x4*)d_in[0];
    const float* W0 = (const float*)d_in[4];
    const float* b0 = (const float*)d_in[5];
    const float* W1 = (const float*)d_in[6];
    const float* b1 = (const float*)d_in[7];
    const float* W2 = (const float*)d_in[8];
    const float* b2 = (const float*)d_in[9];
    const float* Wf = (const float*)d_in[10];
    const float* bf = (const float*)d_in[11];
    f32x4* out = (f32x4*)d_out;

    float* rtab = (float*)d_ws;                               // 65504 B
    // counter lives INSIDE the proven-available 64 KiB (65504 + 4 <= 65536)
    unsigned int* cnt = (unsigned int*)((char*)d_ws + 65504);

    hipMemsetAsync(cnt, 0, sizeof(unsigned int), stream);
    fused<<<256, 1024, 0, stream>>>(mask, W0, b0, W1, b1, W2, b2, Wf, bf,
                                    rtab, cnt, out);
}

// Round 9
// 31.300 us; speedup vs baseline: 5.4434x; 1.5475x over previous
//
#include <hip/hip_runtime.h>
#include <hip/hip_bf16.h>

// out[b,h,i,j] = mask[b,h,i,j] - bias[h, i-j]
// bias depends only on d = i-j+1023 -> 8 x 2047 table (64 KiB), stored
// REVERSED: rtab[h][1023-i+j] so a row's j-sweep is ascending contiguous.
//
// Two-kernel structure (best measured: R4 = 31.3 us). This round's single
// change: NONTEMPORAL STORES in apply (loads stay cached). R2 showed NT on
// both directions regresses (NT loads bypass L3 and double HBM fetch);
// NT store-only keeps the mask L3-resident while the write stream skips
// cache allocation.

#define L_SEQ 1024
#define NDIAG (2 * L_SEQ - 1)   // 2047
#define NH 8
#define DIM 64

typedef float f32x4 __attribute__((ext_vector_type(4)));
typedef float f32x4u __attribute__((ext_vector_type(4), aligned(4)));

__device__ __forceinline__ float silu_f(float x) {
    return x / (1.0f + __expf(-x));
}

// 4 diagonals per 256-thread block; 64 lanes per diagonal.
__global__ __launch_bounds__(256) void build_bias_table(
    const float* __restrict__ W0, const float* __restrict__ b0,
    const float* __restrict__ W1, const float* __restrict__ b1,
    const float* __restrict__ W2, const float* __restrict__ b2,
    const float* __restrict__ Wf, const float* __restrict__ bf,
    float* __restrict__ rtab /* [NH][NDIAG], reversed */) {
    const int g = threadIdx.x >> 6;      // diag group 0..3
    const int t = threadIdx.x & 63;      // 0..63
    const int d = blockIdx.x * 4 + g;    // 0..2047 (guard 2047)
    const float rel = (float)(d - (L_SEQ - 1));

    __shared__ float sh[4][DIM];

    float h = silu_f(rel * W0[t] + b0[t]);
    sh[g][t] = h;
    __syncthreads();

    float acc = b1[t];
    #pragma unroll
    for (int k = 0; k < DIM; ++k) acc += sh[g][k] * W1[k * DIM + t];
    float h1 = silu_f(acc);
    __syncthreads();
    sh[g][t] = h1;
    __syncthreads();

    acc = b2[t];
    #pragma unroll
    for (int k = 0; k < DIM; ++k) acc += sh[g][k] * W2[k * DIM + t];
    float h2 = silu_f(acc);
    __syncthreads();
    sh[g][t] = h2;
    __syncthreads();

    if (t < NH && d < NDIAG) {
        float a = bf[t];
        #pragma unroll
        for (int k = 0; k < DIM; ++k) a += sh[g][k] * Wf[k * NH + t];
        rtab[t * NDIAG + (NDIAG - 1 - d)] = a;
    }
}

// One block per output row (b,h,i). Thread t handles j = 4t..4t+3.
// Cached loads (mask stays L3-resident), NONTEMPORAL store (write stream
// skips cache allocation -> no eviction pressure on the read stream).
__global__ __launch_bounds__(256) void apply_bias(
    const f32x4* __restrict__ mask, const float* __restrict__ rtab,
    f32x4* __restrict__ out) {
    const int row = blockIdx.x;               // 0 .. B*NH*L-1
    const int i = row & (L_SEQ - 1);
    const int h = (row >> 10) & (NH - 1);
    const float* rt = rtab + h * NDIAG + (L_SEQ - 1 - i);

    const int t = threadIdx.x;
    const int idx = row * 256 + t;

    const f32x4u v = *(const f32x4u*)(rt + (t << 2));  // bias[h,i,4t..4t+3]
    const f32x4 m = mask[idx];
    f32x4 o;
    o.x = m.x - v.x;
    o.y = m.y - v.y;
    o.z = m.z - v.z;
    o.w = m.w - v.w;
    __builtin_nontemporal_store(o, &out[idx]);
}

extern "C" void kernel_launch(void* const* d_in, const int* in_sizes, int n_in,
                              void* d_out, int out_size, void* d_ws, size_t ws_size,
                              hipStream_t stream) {
    const float* mask = (const float*)d_in[0];
    const float* W0 = (const float*)d_in[4];
    const float* b0 = (const float*)d_in[5];
    const float* W1 = (const float*)d_in[6];
    const float* b1 = (const float*)d_in[7];
    const float* W2 = (const float*)d_in[8];
    const float* b2 = (const float*)d_in[9];
    const float* Wf = (const float*)d_in[10];
    const float* bf = (const float*)d_in[11];
    float* out = (float*)d_out;

    float* rtab = (float*)d_ws;   // NH * NDIAG floats = 64 KiB

    build_bias_table<<<(NDIAG + 3) / 4, 256, 0, stream>>>(
        W0, b0, W1, b1, W2, b2, Wf, bf, rtab);

    const int rows = out_size / L_SEQ;   // B*NH*L = 16384
    apply_bias<<<rows, 256, 0, stream>>>(
        (const f32x4*)mask, rtab, (f32x4*)out);
}